// Round 12
// baseline (268.371 us; speedup 1.0000x reference)
//
#include <hip/hip_runtime.h>
#include <stdint.h>

typedef unsigned short u16;

#define Bb 4
#define Hh 4
#define Tt 8
#define Cc 256
#define NP 196
#define Ss 1568                 // Tt*NP
#define SCALE_S 0.0252538136f   // 1/sqrt(1568)

typedef __attribute__((ext_vector_type(4))) float floatx4;
typedef __attribute__((ext_vector_type(8))) short shortx8;

__device__ __forceinline__ float bf2f(u16 u) {
    union { unsigned u; float f; } v; v.u = ((unsigned)u) << 16; return v.f;
}
__device__ __forceinline__ u16 f2bf(float f) {
    union { float f; unsigned u; } v; v.f = f;
    unsigned r = v.u + 0x7FFFu + ((v.u >> 16) & 1u);
    return (u16)(r >> 16);
}

// async global->LDS, 16B/lane. Dest pattern: wave-uniform base + lane*16 (HW constraint).
__device__ __forceinline__ void gl_lds16(const u16* src, u16* dst) {
    __builtin_amdgcn_global_load_lds(
        (__attribute__((address_space(1))) void*)(uintptr_t)src,
        (__attribute__((address_space(3))) void*)(uint32_t)(uintptr_t)dst,
        16, 0, 0);
}

// Stage a 128x32 bf16 tile into LDS [128][32]. chunk = tid + j*256:
// LDS offset = chunk*16B = wave-uniform + lane*16 — satisfies the HW dest rule.
__device__ __forceinline__ void stage_gl(const u16* gbase, int ld, int row_base,
                                         int row_last, int col0, u16* lds, int tid) {
#pragma unroll
    for (int j = 0; j < 2; ++j) {
        int chunk = tid + j * 256;        // 0..511
        int row   = chunk >> 2;           // 0..127
        int col   = (chunk & 3) << 3;     // 0,8,16,24
        int grow  = row_base + row; grow = grow <= row_last ? grow : row_last;
        gl_lds16(gbase + (size_t)grow * ld + col0 + col, lds + chunk * 8);
    }
}

// ---- K0: fp32 -> bf16 convert (weights) ----
__global__ __launch_bounds__(256) void k_convw(const float* __restrict__ src, u16* __restrict__ dst, int n) {
    int i = blockIdx.x * 256 + threadIdx.x;
    if (i < n) dst[i] = f2bf(src[i]);
}

// One BK=32 step: 4x4 grid of 16x16x32 bf16 MFMAs per wave (wave covers 64x64).
__device__ __forceinline__ void mfma_step(const u16* As, const u16* Bs, int lane,
                                          int wm, int wn, floatx4 acc[4][4]) {
    const int r15 = lane & 15;
    const int kq  = (lane >> 4) << 3;
    shortx8 a[4], b[4];
#pragma unroll
    for (int i = 0; i < 4; ++i)
        a[i] = *(const shortx8*)(As + (wm * 64 + i * 16 + r15) * 32 + kq);
#pragma unroll
    for (int j = 0; j < 4; ++j)
        b[j] = *(const shortx8*)(Bs + (wn * 64 + j * 16 + r15) * 32 + kq);
#pragma unroll
    for (int i = 0; i < 4; ++i)
#pragma unroll
        for (int j = 0; j < 4; ++j)
            acc[i][j] = __builtin_amdgcn_mfma_f32_16x16x32_bf16(a[i], b[j], acc[i][j], 0, 0, 0);
}

// C[m,n] = sum_k A[m,k]*B[n,k], 128x128 tile, async global_load_lds staging (m97).
__device__ __forceinline__ void gemm_bt_core(const u16* A, const u16* Bm, int lda, int ldb,
                                             int mbase, int mlast, int nbase, int nlast,
                                             int KD, u16* As, u16* Bs, floatx4 acc[4][4]) {
    int tid = threadIdx.x;
    int lane = tid & 63, wave = tid >> 6, wm = wave >> 1, wn = wave & 1;
    for (int k0 = 0; k0 < KD; k0 += 32) {
        stage_gl(A,  lda, mbase, mlast, k0, As, tid);
        stage_gl(Bm, ldb, nbase, nlast, k0, Bs, tid);
        __syncthreads();                       // staging visible (vmcnt drained)
        mfma_step(As, Bs, lane, wm, wn, acc);
        __syncthreads();                       // reads done before next overwrite
    }
}

// ---- K1: emb fp32 [B,T,C,N] -> x bf16 [B,S,C] ----
__global__ void k_transpose(const float* __restrict__ emb, u16* __restrict__ x) {
    __shared__ u16 tile[32][33];
    int bt = blockIdx.z;
    int c0 = blockIdx.y * 32, n0 = blockIdx.x * 32;
    const float* src = emb + (size_t)bt * Cc * NP;
#pragma unroll
    for (int rr = 0; rr < 32; rr += 8) {
        int c = c0 + threadIdx.y + rr;
        int n = n0 + threadIdx.x;
        u16 v = 0;
        if (n < NP) v = f2bf(src[(size_t)c * NP + n]);
        tile[threadIdx.y + rr][threadIdx.x] = v;
    }
    __syncthreads();
    int b = bt / Tt, t = bt % Tt;
    u16* dst = x + ((size_t)b * Ss + (size_t)t * NP) * Cc;
#pragma unroll
    for (int rr = 0; rr < 32; rr += 8) {
        int n = n0 + threadIdx.y + rr;
        int c = c0 + threadIdx.x;
        if (n < NP) dst[(size_t)n * Cc + c] = tile[threadIdx.x][threadIdx.y + rr];
    }
}

// ---- K2: QKV projections, all (qkv,b,h) parallel. V written transposed [C,S]. ----
__global__ __launch_bounds__(256) void k_qkv(const u16* __restrict__ x,
                                             const u16* __restrict__ Wq,
                                             const u16* __restrict__ Wk,
                                             const u16* __restrict__ Wv,
                                             u16* __restrict__ Q, u16* __restrict__ Kb,
                                             u16* __restrict__ Vt) {
    __shared__ __align__(16) u16 As[128 * 32], Bs[128 * 32];
    floatx4 acc[4][4];
#pragma unroll
    for (int i = 0; i < 4; ++i)
#pragma unroll
        for (int j = 0; j < 4; ++j) acc[i][j] = (floatx4)(0.f);
    int z = blockIdx.z;
    int qkv = z >> 4, bh = z & 15, b = bh >> 2, h = bh & 3;
    const u16* A = x + (size_t)b * Ss * Cc;
    const u16* W = (qkv == 0 ? Wq : (qkv == 1 ? Wk : Wv)) + (size_t)h * Cc * Cc;
    int mbase = blockIdx.y * 128, nbase = blockIdx.x * 128;
    gemm_bt_core(A, W, Cc, Cc, mbase, Ss - 1, nbase, Cc - 1, Cc, As, Bs, acc);

    int tid = threadIdx.x, lane = tid & 63, wave = tid >> 6, wm = wave >> 1, wn = wave & 1;
    int rq = (lane >> 4) << 2, cn = lane & 15;
    if (qkv < 2) {
        u16* out = (qkv == 0 ? Q : Kb) + (size_t)bh * Ss * Cc;
#pragma unroll
        for (int i = 0; i < 4; ++i) {
            int mb = mbase + wm * 64 + i * 16 + rq;
#pragma unroll
            for (int j = 0; j < 4; ++j) {
                int n = nbase + wn * 64 + j * 16 + cn;
#pragma unroll
                for (int r = 0; r < 4; ++r) {
                    int m = mb + r;
                    if (m < Ss) out[(size_t)m * Cc + n] = f2bf(acc[i][j][r]);
                }
            }
        }
    } else {
        u16* out = Vt + (size_t)bh * Cc * Ss;
#pragma unroll
        for (int i = 0; i < 4; ++i) {
            int m0 = mbase + wm * 64 + i * 16 + rq;
            if (m0 < Ss) {
#pragma unroll
                for (int j = 0; j < 4; ++j) {
                    int n = nbase + wn * 64 + j * 16 + cn;
                    ushort4 v;
                    v.x = f2bf(acc[i][j][0]); v.y = f2bf(acc[i][j][1]);
                    v.z = f2bf(acc[i][j][2]); v.w = f2bf(acc[i][j][3]);
                    *(ushort4*)(out + (size_t)n * Ss + m0) = v;
                }
            }
        }
    }
}

// ---- K3: Sc = (Q K^T)*SCALE_S -> bf16, + fp32 sum/sumsq atomics per (b,h) ----
__global__ __launch_bounds__(256) void k_scores(const u16* __restrict__ Q,
                                                const u16* __restrict__ Kb,
                                                u16* __restrict__ Sc, float* __restrict__ stats) {
    __shared__ __align__(16) u16 As[128 * 32], Bs[128 * 32];
    __shared__ float sred[8];
    floatx4 acc[4][4];
#pragma unroll
    for (int i = 0; i < 4; ++i)
#pragma unroll
        for (int j = 0; j < 4; ++j) acc[i][j] = (floatx4)(0.f);
    int bh = blockIdx.z;
    const u16* A  = Q  + (size_t)bh * Ss * Cc;
    const u16* Bm = Kb + (size_t)bh * Ss * Cc;
    int mbase = blockIdx.y * 128, nbase = blockIdx.x * 128;
    gemm_bt_core(A, Bm, Cc, Cc, mbase, Ss - 1, nbase, Ss - 1, Cc, As, Bs, acc);

    int tid = threadIdx.x, lane = tid & 63, wave = tid >> 6, wm = wave >> 1, wn = wave & 1;
    int rq = (lane >> 4) << 2, cn = lane & 15;
    u16* out = Sc + (size_t)bh * Ss * Ss;
    float lsum = 0.f, lsq = 0.f;
#pragma unroll
    for (int i = 0; i < 4; ++i) {
        int mb = mbase + wm * 64 + i * 16 + rq;
#pragma unroll
        for (int j = 0; j < 4; ++j) {
            int n = nbase + wn * 64 + j * 16 + cn;
            bool nv = n < Ss;
#pragma unroll
            for (int r = 0; r < 4; ++r) {
                int m = mb + r;
                if (nv && m < Ss) {
                    float v = acc[i][j][r] * SCALE_S;
                    out[(size_t)m * Ss + n] = f2bf(v);
                    lsum += v; lsq += v * v;
                }
            }
        }
    }
#pragma unroll
    for (int mk = 1; mk <= 32; mk <<= 1) { lsum += __shfl_xor(lsum, mk); lsq += __shfl_xor(lsq, mk); }
    if (lane == 0) { sred[wave] = lsum; sred[4 + wave] = lsq; }
    __syncthreads();
    if (tid == 0) atomicAdd(&stats[bh * 4 + 0], sred[0] + sred[1] + sred[2] + sred[3]);
    if (tid == 1) atomicAdd(&stats[bh * 4 + 1], sred[4] + sred[5] + sred[6] + sred[7]);
}

// ---- K4: finalize per-(b,h) mean / inv-std ----
__global__ void k_stats(float* __restrict__ stats) {
    int i = threadIdx.x;
    if (i < 16) {
        float inv  = 1.f / ((float)Ss * (float)Ss);
        float mean = stats[i * 4] * inv;
        float var  = stats[i * 4 + 1] * inv - mean * mean;
        var = fmaxf(var, 0.f);
        stats[i * 4 + 2] = mean;
        stats[i * 4 + 3] = rsqrtf(var + 1e-5f);
    }
}

// ---- K5: ctx = softmax(norm(Sc)) @ V. exp fused into A-staging; V via async LDS. ----
__global__ __launch_bounds__(256) void k_pv(const u16* __restrict__ Sc,
                                            const u16* __restrict__ Vt,
                                            const float* __restrict__ stats,
                                            u16* __restrict__ ctx) {
    __shared__ __align__(16) u16 As[128 * 32], Bs[128 * 32];
    __shared__ float rs[128];
    floatx4 acc[4][4];
#pragma unroll
    for (int i = 0; i < 4; ++i)
#pragma unroll
        for (int j = 0; j < 4; ++j) acc[i][j] = (floatx4)(0.f);
    int bh = blockIdx.z;
    float mean = stats[bh * 4 + 2], istd = stats[bh * 4 + 3];
    float aa = istd * 1.44269504f;   // log2(e)*istd
    float bb = -mean * aa;
    const u16* A  = Sc + (size_t)bh * Ss * Ss;   // [S][S]
    const u16* Bm = Vt + (size_t)bh * Cc * Ss;   // [C][S]
    int mbase = blockIdx.y * 128, nbase = blockIdx.x * 128;
    int tid = threadIdx.x, lane = tid & 63, wave = tid >> 6, wm = wave >> 1, wn = wave & 1;
    int row0 = tid >> 2, row1 = 64 + (tid >> 2);
    int cole = (tid & 3) << 3;
    float rsum0 = 0.f, rsum1 = 0.f;

    for (int k0 = 0; k0 < Ss; k0 += 32) {
        // A rows -> regs, exp transform (no LDS touch yet)
        int ga0 = mbase + row0; ga0 = ga0 <= Ss - 1 ? ga0 : Ss - 1;
        int ga1 = mbase + row1; ga1 = ga1 <= Ss - 1 ? ga1 : Ss - 1;
        shortx8 v0 = *(const shortx8*)(A + (size_t)ga0 * Ss + k0 + cole);
        shortx8 v1 = *(const shortx8*)(A + (size_t)ga1 * Ss + k0 + cole);
        shortx8 o0, o1;
        float p0 = 0.f, p1 = 0.f;
#pragma unroll
        for (int e = 0; e < 8; ++e) {
            float f0 = bf2f((u16)v0[e]);
            float e0 = exp2f(f0 * aa + bb);
            p0 += e0; o0[e] = (short)f2bf(e0);
            float f1 = bf2f((u16)v1[e]);
            float e1 = exp2f(f1 * aa + bb);
            p1 += e1; o1[e] = (short)f2bf(e1);
        }
        rsum0 += p0; rsum1 += p1;
        __syncthreads();                       // prior iter's LDS reads done
        *(shortx8*)(As + row0 * 32 + cole) = o0;
        *(shortx8*)(As + row1 * 32 + cole) = o1;
        stage_gl(Bm, Ss, nbase, Cc - 1, k0, Bs, tid);   // async V staging
        __syncthreads();                       // both stagings visible
        mfma_step(As, Bs, lane, wm, wn, acc);
    }
    rsum0 += __shfl_xor(rsum0, 1); rsum0 += __shfl_xor(rsum0, 2);
    rsum1 += __shfl_xor(rsum1, 1); rsum1 += __shfl_xor(rsum1, 2);
    __syncthreads();
    if ((tid & 3) == 0) { rs[tid >> 2] = rsum0; rs[64 + (tid >> 2)] = rsum1; }
    __syncthreads();

    u16* out = ctx + (size_t)bh * Ss * Cc;
    int rq = (lane >> 4) << 2, cn = lane & 15;
#pragma unroll
    for (int i = 0; i < 4; ++i) {
        int ml = wm * 64 + i * 16 + rq;
#pragma unroll
        for (int r = 0; r < 4; ++r) {
            int m = mbase + ml + r;
            if (m < Ss) {
                float invs = 1.f / rs[ml + r];
#pragma unroll
                for (int j = 0; j < 4; ++j) {
                    int n = nbase + wn * 64 + j * 16 + cn;
                    out[(size_t)m * Cc + n] = f2bf(acc[i][j][r] * invs);
                }
            }
        }
    }
}

// ---- K6a: mean over heads: ctx bf16 [B,H,S,C] -> ctxm bf16 [B,S,C] ----
__global__ __launch_bounds__(256) void k_hmean(const u16* __restrict__ ctx, u16* __restrict__ ctxm) {
    int i = blockIdx.x * 256 + threadIdx.x;
    const int PB = Ss * Cc / 4;
    int b = i / PB, g = i % PB;
    float a0 = 0.f, a1 = 0.f, a2 = 0.f, a3 = 0.f;
#pragma unroll
    for (int h = 0; h < Hh; ++h) {
        ushort4 v = *((const ushort4*)(ctx + ((size_t)(b * Hh + h)) * Ss * Cc) + g);
        a0 += bf2f(v.x); a1 += bf2f(v.y); a2 += bf2f(v.z); a3 += bf2f(v.w);
    }
    ushort4 o;
    o.x = f2bf(a0 * 0.25f); o.y = f2bf(a1 * 0.25f);
    o.z = f2bf(a2 * 0.25f); o.w = f2bf(a3 * 0.25f);
    *((ushort4*)(ctxm + (size_t)b * Ss * Cc) + g) = o;
}

// ---- K6b: O = ctxm @ Wo^T -> fp32 d_out (flat [B,S,C] == [B,T,C,N]) ----
__global__ __launch_bounds__(256) void k_out(const u16* __restrict__ ctxm,
                                             const u16* __restrict__ Wo, float* __restrict__ out) {
    __shared__ __align__(16) u16 As[128 * 32], Bs[128 * 32];
    floatx4 acc[4][4];
#pragma unroll
    for (int i = 0; i < 4; ++i)
#pragma unroll
        for (int j = 0; j < 4; ++j) acc[i][j] = (floatx4)(0.f);
    int b = blockIdx.z;
    const u16* A = ctxm + (size_t)b * Ss * Cc;
    int mbase = blockIdx.y * 128, nbase = blockIdx.x * 128;
    gemm_bt_core(A, Wo, Cc, Cc, mbase, Ss - 1, nbase, Cc - 1, Cc, As, Bs, acc);

    int tid = threadIdx.x, lane = tid & 63, wave = tid >> 6, wm = wave >> 1, wn = wave & 1;
    int rq = (lane >> 4) << 2, cn = lane & 15;
    float* o = out + (size_t)b * Ss * Cc;
#pragma unroll
    for (int i = 0; i < 4; ++i) {
        int mb = mbase + wm * 64 + i * 16 + rq;
#pragma unroll
        for (int j = 0; j < 4; ++j) {
            int n = nbase + wn * 64 + j * 16 + cn;
#pragma unroll
            for (int r = 0; r < 4; ++r) {
                int m = mb + r;
                if (m < Ss) o[(size_t)m * Cc + n] = acc[i][j][r];   // fp32 store
            }
        }
    }
}

extern "C" void kernel_launch(void* const* d_in, const int* in_sizes, int n_in,
                              void* d_out, int out_size, void* d_ws, size_t ws_size,
                              hipStream_t stream) {
    const float* emb = (const float*)d_in[0];
    float* out = (float*)d_out;

    char* ws = (char*)d_ws;
    size_t off = 0;
    auto alloc = [&](size_t bytes) -> void* {
        void* p = ws + off;
        off = (off + bytes + 255) & ~(size_t)255;
        return p;
    };
    float* stats = (float*)alloc(16 * 4 * sizeof(float));
    u16* Wqc  = (u16*)alloc((size_t)Hh * Cc * Cc * 2);
    u16* Wkc  = (u16*)alloc((size_t)Hh * Cc * Cc * 2);
    u16* Wvc  = (u16*)alloc((size_t)Hh * Cc * Cc * 2);
    u16* Woc  = (u16*)alloc((size_t)Cc * Cc * 2);
    u16* x    = (u16*)alloc((size_t)Bb * Ss * Cc * 2);            // 3.2 MB
    u16* Q    = (u16*)alloc((size_t)Bb * Hh * Ss * Cc * 2);       // 12.8 MB (reused as ctx)
    u16* Kb   = (u16*)alloc((size_t)Bb * Hh * Ss * Cc * 2);       // 12.8 MB
    u16* Vt   = (u16*)alloc((size_t)Bb * Hh * Ss * Cc * 2);       // 12.8 MB ([C,S])
    u16* ctxm = (u16*)alloc((size_t)Bb * Ss * Cc * 2);            // 3.2 MB
    u16* Sc   = (u16*)alloc((size_t)Bb * Hh * Ss * Ss * 2);       // 78.7 MB
    u16* ctx  = Q;   // alias

    hipMemsetAsync(stats, 0, 16 * 4 * sizeof(float), stream);

    k_convw<<<dim3(1024), dim3(256), 0, stream>>>((const float*)d_in[1], Wqc, Hh * Cc * Cc);
    k_convw<<<dim3(1024), dim3(256), 0, stream>>>((const float*)d_in[2], Wkc, Hh * Cc * Cc);
    k_convw<<<dim3(1024), dim3(256), 0, stream>>>((const float*)d_in[3], Wvc, Hh * Cc * Cc);
    k_convw<<<dim3(256),  dim3(256), 0, stream>>>((const float*)d_in[4], Woc, Cc * Cc);

    k_transpose<<<dim3(7, 8, 32), dim3(32, 8), 0, stream>>>(emb, x);
    k_qkv<<<dim3(2, 13, 48), dim3(256), 0, stream>>>(x, Wqc, Wkc, Wvc, Q, Kb, Vt);
    k_scores<<<dim3(13, 13, 16), dim3(256), 0, stream>>>(Q, Kb, Sc, stats);
    k_stats<<<dim3(1), dim3(64), 0, stream>>>(stats);
    k_pv<<<dim3(2, 13, 16), dim3(256), 0, stream>>>(Sc, Vt, stats, ctx);
    k_hmean<<<dim3(1568), dim3(256), 0, stream>>>(ctx, ctxm);
    k_out<<<dim3(2, 13, 4), dim3(256), 0, stream>>>(ctxm, Woc, out);
}

// Round 13
// 255.137 us; speedup vs baseline: 1.0519x; 1.0519x over previous
//
#include <hip/hip_runtime.h>
#include <stdint.h>

typedef unsigned short u16;

#define Bb 4
#define Hh 4
#define Tt 8
#define Cc 256
#define NP 196
#define Ss 1568                 // Tt*NP
#define SCALE_S 0.0252538136f   // 1/sqrt(1568)

typedef __attribute__((ext_vector_type(4))) float floatx4;
typedef __attribute__((ext_vector_type(8))) short shortx8;

__device__ __forceinline__ float bf2f(u16 u) {
    union { unsigned u; float f; } v; v.u = ((unsigned)u) << 16; return v.f;
}
__device__ __forceinline__ u16 f2bf(float f) {
    union { float f; unsigned u; } v; v.f = f;
    unsigned r = v.u + 0x7FFFu + ((v.u >> 16) & 1u);
    return (u16)(r >> 16);
}

// ---- K0: fp32 -> bf16 convert (weights) ----
__global__ __launch_bounds__(256) void k_convw(const float* __restrict__ src, u16* __restrict__ dst, int n) {
    int i = blockIdx.x * 256 + threadIdx.x;
    if (i < n) dst[i] = f2bf(src[i]);
}

// One BK=32 step: 4x4 grid of 16x16x32 bf16 MFMAs per wave (wave covers 64x64).
__device__ __forceinline__ void mfma_step(const u16* As, const u16* Bs, int lane,
                                          int wm, int wn, floatx4 acc[4][4]) {
    const int r15 = lane & 15;
    const int kq  = (lane >> 4) << 3;
    shortx8 a[4], b[4];
#pragma unroll
    for (int i = 0; i < 4; ++i)
        a[i] = *(const shortx8*)(As + (wm * 64 + i * 16 + r15) * 32 + kq);
#pragma unroll
    for (int j = 0; j < 4; ++j)
        b[j] = *(const shortx8*)(Bs + (wn * 64 + j * 16 + r15) * 32 + kq);
#pragma unroll
    for (int i = 0; i < 4; ++i)
#pragma unroll
        for (int j = 0; j < 4; ++j)
            acc[i][j] = __builtin_amdgcn_mfma_f32_16x16x32_bf16(a[i], b[j], acc[i][j], 0, 0, 0);
}

// C[m,n] = sum_k A[m,k]*B[n,k], 128x128 tile, SOFTWARE-PIPELINED register staging:
// loads for k+1 issue between publishing k and the MFMA of k -> fly during MFMA.
__device__ __forceinline__ void gemm_bt_core(const u16* A, const u16* Bm, int lda, int ldb,
                                             int mbase, int mlast, int nbase, int nlast,
                                             int KD, u16* As, u16* Bs, floatx4 acc[4][4]) {
    int tid = threadIdx.x;
    int lane = tid & 63, wave = tid >> 6, wm = wave >> 1, wn = wave & 1;
    int row0 = tid >> 2, row1 = 64 + (tid >> 2);
    int cole = (tid & 3) << 3;                 // 0,8,16,24
    int ga0 = mbase + row0; ga0 = ga0 <= mlast ? ga0 : mlast;
    int ga1 = mbase + row1; ga1 = ga1 <= mlast ? ga1 : mlast;
    int gb0 = nbase + row0; gb0 = gb0 <= nlast ? gb0 : nlast;
    int gb1 = nbase + row1; gb1 = gb1 <= nlast ? gb1 : nlast;
    const u16* pa0 = A  + (size_t)ga0 * lda + cole;
    const u16* pa1 = A  + (size_t)ga1 * lda + cole;
    const u16* pb0 = Bm + (size_t)gb0 * ldb + cole;
    const u16* pb1 = Bm + (size_t)gb1 * ldb + cole;
    shortx8 va0 = *(const shortx8*)(pa0);
    shortx8 va1 = *(const shortx8*)(pa1);
    shortx8 vb0 = *(const shortx8*)(pb0);
    shortx8 vb1 = *(const shortx8*)(pb1);
    for (int k0 = 0; k0 < KD; k0 += 32) {
        __syncthreads();                       // prior iter's LDS reads done
        *(shortx8*)(As + row0 * 32 + cole) = va0;
        *(shortx8*)(As + row1 * 32 + cole) = va1;
        *(shortx8*)(Bs + row0 * 32 + cole) = vb0;
        *(shortx8*)(Bs + row1 * 32 + cole) = vb1;
        int k1 = k0 + 32;
        if (k1 < KD) {                         // prefetch next tile (flies during MFMA)
            va0 = *(const shortx8*)(pa0 + k1);
            va1 = *(const shortx8*)(pa1 + k1);
            vb0 = *(const shortx8*)(pb0 + k1);
            vb1 = *(const shortx8*)(pb1 + k1);
        }
        __syncthreads();                       // staging visible
        mfma_step(As, Bs, lane, wm, wn, acc);
    }
}

// ---- K1: emb fp32 [B,T,C,N] -> x bf16 [B,S,C] ----
__global__ void k_transpose(const float* __restrict__ emb, u16* __restrict__ x) {
    __shared__ u16 tile[32][33];
    int bt = blockIdx.z;
    int c0 = blockIdx.y * 32, n0 = blockIdx.x * 32;
    const float* src = emb + (size_t)bt * Cc * NP;
#pragma unroll
    for (int rr = 0; rr < 32; rr += 8) {
        int c = c0 + threadIdx.y + rr;
        int n = n0 + threadIdx.x;
        u16 v = 0;
        if (n < NP) v = f2bf(src[(size_t)c * NP + n]);
        tile[threadIdx.y + rr][threadIdx.x] = v;
    }
    __syncthreads();
    int b = bt / Tt, t = bt % Tt;
    u16* dst = x + ((size_t)b * Ss + (size_t)t * NP) * Cc;
#pragma unroll
    for (int rr = 0; rr < 32; rr += 8) {
        int n = n0 + threadIdx.y + rr;
        int c = c0 + threadIdx.x;
        if (n < NP) dst[(size_t)n * Cc + c] = tile[threadIdx.x][threadIdx.y + rr];
    }
}

// ---- K2: QKV projections, all (qkv,b,h) parallel. V written transposed [C,S]. ----
__global__ __launch_bounds__(256) void k_qkv(const u16* __restrict__ x,
                                             const u16* __restrict__ Wq,
                                             const u16* __restrict__ Wk,
                                             const u16* __restrict__ Wv,
                                             u16* __restrict__ Q, u16* __restrict__ Kb,
                                             u16* __restrict__ Vt) {
    __shared__ __align__(16) u16 As[128 * 32], Bs[128 * 32];
    floatx4 acc[4][4];
#pragma unroll
    for (int i = 0; i < 4; ++i)
#pragma unroll
        for (int j = 0; j < 4; ++j) acc[i][j] = (floatx4)(0.f);
    int z = blockIdx.z;
    int qkv = z >> 4, bh = z & 15, b = bh >> 2, h = bh & 3;
    const u16* A = x + (size_t)b * Ss * Cc;
    const u16* W = (qkv == 0 ? Wq : (qkv == 1 ? Wk : Wv)) + (size_t)h * Cc * Cc;
    int mbase = blockIdx.y * 128, nbase = blockIdx.x * 128;
    gemm_bt_core(A, W, Cc, Cc, mbase, Ss - 1, nbase, Cc - 1, Cc, As, Bs, acc);

    int tid = threadIdx.x, lane = tid & 63, wave = tid >> 6, wm = wave >> 1, wn = wave & 1;
    int rq = (lane >> 4) << 2, cn = lane & 15;
    if (qkv < 2) {
        u16* out = (qkv == 0 ? Q : Kb) + (size_t)bh * Ss * Cc;
#pragma unroll
        for (int i = 0; i < 4; ++i) {
            int mb = mbase + wm * 64 + i * 16 + rq;
#pragma unroll
            for (int j = 0; j < 4; ++j) {
                int n = nbase + wn * 64 + j * 16 + cn;
#pragma unroll
                for (int r = 0; r < 4; ++r) {
                    int m = mb + r;
                    if (m < Ss) out[(size_t)m * Cc + n] = f2bf(acc[i][j][r]);
                }
            }
        }
    } else {
        u16* out = Vt + (size_t)bh * Cc * Ss;
#pragma unroll
        for (int i = 0; i < 4; ++i) {
            int m0 = mbase + wm * 64 + i * 16 + rq;
            if (m0 < Ss) {
#pragma unroll
                for (int j = 0; j < 4; ++j) {
                    int n = nbase + wn * 64 + j * 16 + cn;
                    ushort4 v;
                    v.x = f2bf(acc[i][j][0]); v.y = f2bf(acc[i][j][1]);
                    v.z = f2bf(acc[i][j][2]); v.w = f2bf(acc[i][j][3]);
                    *(ushort4*)(out + (size_t)n * Ss + m0) = v;
                }
            }
        }
    }
}

// ---- K3: Sc = (Q K^T)*SCALE_S -> bf16, + fp32 sum/sumsq atomics per (b,h) ----
__global__ __launch_bounds__(256) void k_scores(const u16* __restrict__ Q,
                                                const u16* __restrict__ Kb,
                                                u16* __restrict__ Sc, float* __restrict__ stats) {
    __shared__ __align__(16) u16 As[128 * 32], Bs[128 * 32];
    __shared__ float sred[8];
    floatx4 acc[4][4];
#pragma unroll
    for (int i = 0; i < 4; ++i)
#pragma unroll
        for (int j = 0; j < 4; ++j) acc[i][j] = (floatx4)(0.f);
    int bh = blockIdx.z;
    const u16* A  = Q  + (size_t)bh * Ss * Cc;
    const u16* Bm = Kb + (size_t)bh * Ss * Cc;
    int mbase = blockIdx.y * 128, nbase = blockIdx.x * 128;
    gemm_bt_core(A, Bm, Cc, Cc, mbase, Ss - 1, nbase, Ss - 1, Cc, As, Bs, acc);

    int tid = threadIdx.x, lane = tid & 63, wave = tid >> 6, wm = wave >> 1, wn = wave & 1;
    int rq = (lane >> 4) << 2, cn = lane & 15;
    u16* out = Sc + (size_t)bh * Ss * Ss;
    float lsum = 0.f, lsq = 0.f;
#pragma unroll
    for (int i = 0; i < 4; ++i) {
        int mb = mbase + wm * 64 + i * 16 + rq;
#pragma unroll
        for (int j = 0; j < 4; ++j) {
            int n = nbase + wn * 64 + j * 16 + cn;
            bool nv = n < Ss;
#pragma unroll
            for (int r = 0; r < 4; ++r) {
                int m = mb + r;
                if (nv && m < Ss) {
                    float v = acc[i][j][r] * SCALE_S;
                    out[(size_t)m * Ss + n] = f2bf(v);
                    lsum += v; lsq += v * v;
                }
            }
        }
    }
#pragma unroll
    for (int mk = 1; mk <= 32; mk <<= 1) { lsum += __shfl_xor(lsum, mk); lsq += __shfl_xor(lsq, mk); }
    if (lane == 0) { sred[wave] = lsum; sred[4 + wave] = lsq; }
    __syncthreads();
    if (tid == 0) atomicAdd(&stats[bh * 4 + 0], sred[0] + sred[1] + sred[2] + sred[3]);
    if (tid == 1) atomicAdd(&stats[bh * 4 + 1], sred[4] + sred[5] + sred[6] + sred[7]);
}

// ---- K4: finalize per-(b,h) mean / inv-std ----
__global__ void k_stats(float* __restrict__ stats) {
    int i = threadIdx.x;
    if (i < 16) {
        float inv  = 1.f / ((float)Ss * (float)Ss);
        float mean = stats[i * 4] * inv;
        float var  = stats[i * 4 + 1] * inv - mean * mean;
        var = fmaxf(var, 0.f);
        stats[i * 4 + 2] = mean;
        stats[i * 4 + 3] = rsqrtf(var + 1e-5f);
    }
}

// ---- K5: softmax(norm(Sc)) @ V, pipelined; head-mean FUSED via fp32 atomics ----
__global__ __launch_bounds__(256) void k_pv(const u16* __restrict__ Sc,
                                            const u16* __restrict__ Vt,
                                            const float* __restrict__ stats,
                                            float* __restrict__ ctxm) {
    __shared__ __align__(16) u16 As[128 * 32], Bs[128 * 32];
    __shared__ float rs[128];
    floatx4 acc[4][4];
#pragma unroll
    for (int i = 0; i < 4; ++i)
#pragma unroll
        for (int j = 0; j < 4; ++j) acc[i][j] = (floatx4)(0.f);
    int bh = blockIdx.z;
    float mean = stats[bh * 4 + 2], istd = stats[bh * 4 + 3];
    float aa = istd * 1.44269504f;   // log2(e)*istd
    float bb = -mean * aa;
    const u16* A  = Sc + (size_t)bh * Ss * Ss;   // [S][S]
    const u16* Bm = Vt + (size_t)bh * Cc * Ss;   // [C][S]
    int mbase = blockIdx.y * 128, nbase = blockIdx.x * 128;
    int tid = threadIdx.x, lane = tid & 63, wave = tid >> 6, wm = wave >> 1, wn = wave & 1;
    int row0 = tid >> 2, row1 = 64 + (tid >> 2);
    int cole = (tid & 3) << 3;
    int ga0 = mbase + row0; ga0 = ga0 <= Ss - 1 ? ga0 : Ss - 1;
    int ga1 = mbase + row1; ga1 = ga1 <= Ss - 1 ? ga1 : Ss - 1;
    const u16* pa0 = A + (size_t)ga0 * Ss + cole;
    const u16* pa1 = A + (size_t)ga1 * Ss + cole;
    const u16* pb0 = Bm + (size_t)(nbase + row0) * Ss + cole;
    const u16* pb1 = Bm + (size_t)(nbase + row1) * Ss + cole;
    float rsum0 = 0.f, rsum1 = 0.f;
    shortx8 v0 = *(const shortx8*)(pa0);
    shortx8 v1 = *(const shortx8*)(pa1);
    shortx8 vb0 = *(const shortx8*)(pb0);
    shortx8 vb1 = *(const shortx8*)(pb1);

    for (int k0 = 0; k0 < Ss; k0 += 32) {
        shortx8 o0, o1;
        float p0 = 0.f, p1 = 0.f;
#pragma unroll
        for (int e = 0; e < 8; ++e) {
            float f0 = bf2f((u16)v0[e]);
            float e0 = exp2f(f0 * aa + bb);
            p0 += e0; o0[e] = (short)f2bf(e0);
            float f1 = bf2f((u16)v1[e]);
            float e1 = exp2f(f1 * aa + bb);
            p1 += e1; o1[e] = (short)f2bf(e1);
        }
        rsum0 += p0; rsum1 += p1;
        __syncthreads();                       // prior iter's LDS reads done
        *(shortx8*)(As + row0 * 32 + cole) = o0;
        *(shortx8*)(As + row1 * 32 + cole) = o1;
        *(shortx8*)(Bs + row0 * 32 + cole) = vb0;
        *(shortx8*)(Bs + row1 * 32 + cole) = vb1;
        int k1 = k0 + 32;
        if (k1 < Ss) {                         // prefetch next tiles (fly during MFMA)
            v0  = *(const shortx8*)(pa0 + k1);
            v1  = *(const shortx8*)(pa1 + k1);
            vb0 = *(const shortx8*)(pb0 + k1);
            vb1 = *(const shortx8*)(pb1 + k1);
        }
        __syncthreads();                       // staging visible
        mfma_step(As, Bs, lane, wm, wn, acc);
    }
    rsum0 += __shfl_xor(rsum0, 1); rsum0 += __shfl_xor(rsum0, 2);
    rsum1 += __shfl_xor(rsum1, 1); rsum1 += __shfl_xor(rsum1, 2);
    __syncthreads();
    if ((tid & 3) == 0) { rs[tid >> 2] = rsum0; rs[64 + (tid >> 2)] = rsum1; }
    __syncthreads();

    // fused head-mean: ctxm[b,s,c] += 0.25 * p_row_normalized * acc
    int b = bh >> 2;
    float* outp = ctxm + (size_t)b * Ss * Cc;
    int rq = (lane >> 4) << 2, cn = lane & 15;
#pragma unroll
    for (int i = 0; i < 4; ++i) {
        int ml = wm * 64 + i * 16 + rq;
#pragma unroll
        for (int r = 0; r < 4; ++r) {
            int m = mbase + ml + r;
            if (m < Ss) {
                float invs = 0.25f / rs[ml + r];
#pragma unroll
                for (int j = 0; j < 4; ++j) {
                    int n = nbase + wn * 64 + j * 16 + cn;
                    atomicAdd(&outp[(size_t)m * Cc + n], acc[i][j][r] * invs);
                }
            }
        }
    }
}

// ---- K6: O = ctxm(fp32) @ Wo^T -> fp32 d_out (flat [B,S,C] == [B,T,C,N]) ----
__global__ __launch_bounds__(256) void k_out(const float* __restrict__ ctxm,
                                             const u16* __restrict__ Wo, float* __restrict__ out) {
    __shared__ __align__(16) u16 As[128 * 32], Bs[128 * 32];
    floatx4 acc[4][4];
#pragma unroll
    for (int i = 0; i < 4; ++i)
#pragma unroll
        for (int j = 0; j < 4; ++j) acc[i][j] = (floatx4)(0.f);
    int b = blockIdx.z;
    const float* A = ctxm + (size_t)b * Ss * Cc;
    int mbase = blockIdx.y * 128, nbase = blockIdx.x * 128;
    int tid = threadIdx.x, lane = tid & 63, wave = tid >> 6, wm = wave >> 1, wn = wave & 1;
    int row0 = tid >> 2, row1 = 64 + (tid >> 2);
    int cole = (tid & 3) << 3;
    int ga0 = mbase + row0; ga0 = ga0 <= Ss - 1 ? ga0 : Ss - 1;
    int ga1 = mbase + row1; ga1 = ga1 <= Ss - 1 ? ga1 : Ss - 1;
    const float* pa0 = A + (size_t)ga0 * Cc + cole;
    const float* pa1 = A + (size_t)ga1 * Cc + cole;
    const u16* pb0 = Wo + (size_t)(nbase + row0 <= Cc - 1 ? nbase + row0 : Cc - 1) * Cc + cole;
    const u16* pb1 = Wo + (size_t)(nbase + row1 <= Cc - 1 ? nbase + row1 : Cc - 1) * Cc + cole;
    float4 a00 = *(const float4*)(pa0), a01 = *(const float4*)(pa0 + 4);
    float4 a10 = *(const float4*)(pa1), a11 = *(const float4*)(pa1 + 4);
    shortx8 vb0 = *(const shortx8*)(pb0);
    shortx8 vb1 = *(const shortx8*)(pb1);
    for (int k0 = 0; k0 < Cc; k0 += 32) {
        shortx8 o0, o1;
        o0[0] = (short)f2bf(a00.x); o0[1] = (short)f2bf(a00.y); o0[2] = (short)f2bf(a00.z); o0[3] = (short)f2bf(a00.w);
        o0[4] = (short)f2bf(a01.x); o0[5] = (short)f2bf(a01.y); o0[6] = (short)f2bf(a01.z); o0[7] = (short)f2bf(a01.w);
        o1[0] = (short)f2bf(a10.x); o1[1] = (short)f2bf(a10.y); o1[2] = (short)f2bf(a10.z); o1[3] = (short)f2bf(a10.w);
        o1[4] = (short)f2bf(a11.x); o1[5] = (short)f2bf(a11.y); o1[6] = (short)f2bf(a11.z); o1[7] = (short)f2bf(a11.w);
        __syncthreads();
        *(shortx8*)(As + row0 * 32 + cole) = o0;
        *(shortx8*)(As + row1 * 32 + cole) = o1;
        *(shortx8*)(Bs + row0 * 32 + cole) = vb0;
        *(shortx8*)(Bs + row1 * 32 + cole) = vb1;
        int k1 = k0 + 32;
        if (k1 < Cc) {
            a00 = *(const float4*)(pa0 + k1); a01 = *(const float4*)(pa0 + k1 + 4);
            a10 = *(const float4*)(pa1 + k1); a11 = *(const float4*)(pa1 + k1 + 4);
            vb0 = *(const shortx8*)(pb0 + k1);
            vb1 = *(const shortx8*)(pb1 + k1);
        }
        __syncthreads();
        mfma_step(As, Bs, lane, wm, wn, acc);
    }
    int rq = (lane >> 4) << 2, cn = lane & 15;
    float* o = out + (size_t)b * Ss * Cc;
#pragma unroll
    for (int i = 0; i < 4; ++i) {
        int mb = mbase + wm * 64 + i * 16 + rq;
#pragma unroll
        for (int j = 0; j < 4; ++j) {
            int n = nbase + wn * 64 + j * 16 + cn;
#pragma unroll
            for (int r = 0; r < 4; ++r) {
                int m = mb + r;
                if (m < Ss) o[(size_t)m * Cc + n] = acc[i][j][r];   // fp32 store
            }
        }
    }
}

extern "C" void kernel_launch(void* const* d_in, const int* in_sizes, int n_in,
                              void* d_out, int out_size, void* d_ws, size_t ws_size,
                              hipStream_t stream) {
    const float* emb = (const float*)d_in[0];
    float* out = (float*)d_out;

    char* ws = (char*)d_ws;
    size_t off = 0;
    auto alloc = [&](size_t bytes) -> void* {
        void* p = ws + off;
        off = (off + bytes + 255) & ~(size_t)255;
        return p;
    };
    // Total ~122.6 MiB
    float* stats = (float*)alloc(16 * 4 * sizeof(float));
    u16* Wqc  = (u16*)alloc((size_t)Hh * Cc * Cc * 2);
    u16* Wkc  = (u16*)alloc((size_t)Hh * Cc * Cc * 2);
    u16* Wvc  = (u16*)alloc((size_t)Hh * Cc * Cc * 2);
    u16* Woc  = (u16*)alloc((size_t)Cc * Cc * 2);
    u16* x    = (u16*)alloc((size_t)Bb * Ss * Cc * 2);            // 3.1 MiB
    u16* Q    = (u16*)alloc((size_t)Bb * Hh * Ss * Cc * 2);       // 12.25 MiB
    u16* Kb   = (u16*)alloc((size_t)Bb * Hh * Ss * Cc * 2);       // 12.25 MiB
    u16* Vt   = (u16*)alloc((size_t)Bb * Hh * Ss * Cc * 2);       // 12.25 MiB ([C,S])
    float* ctxm = (float*)alloc((size_t)Bb * Ss * Cc * 4);        // 6.1 MiB fp32 head-mean accum
    u16* Sc   = (u16*)alloc((size_t)Bb * Hh * Ss * Ss * 2);       // 75.0 MiB

    hipMemsetAsync(stats, 0, 16 * 4 * sizeof(float), stream);
    hipMemsetAsync(ctxm, 0, (size_t)Bb * Ss * Cc * 4, stream);

    k_convw<<<dim3(1024), dim3(256), 0, stream>>>((const float*)d_in[1], Wqc, Hh * Cc * Cc);
    k_convw<<<dim3(1024), dim3(256), 0, stream>>>((const float*)d_in[2], Wkc, Hh * Cc * Cc);
    k_convw<<<dim3(1024), dim3(256), 0, stream>>>((const float*)d_in[3], Wvc, Hh * Cc * Cc);
    k_convw<<<dim3(256),  dim3(256), 0, stream>>>((const float*)d_in[4], Woc, Cc * Cc);

    k_transpose<<<dim3(7, 8, 32), dim3(32, 8), 0, stream>>>(emb, x);
    k_qkv<<<dim3(2, 13, 48), dim3(256), 0, stream>>>(x, Wqc, Wkc, Wvc, Q, Kb, Vt);
    k_scores<<<dim3(13, 13, 16), dim3(256), 0, stream>>>(Q, Kb, Sc, stats);
    k_stats<<<dim3(1), dim3(64), 0, stream>>>(stats);
    k_pv<<<dim3(2, 13, 16), dim3(256), 0, stream>>>(Sc, Vt, stats, ctxm);
    k_out<<<dim3(2, 13, 4), dim3(256), 0, stream>>>(ctxm, Woc, out);
}